// Round 7
// baseline (913.861 us; speedup 1.0000x reference)
//
#include <hip/hip_runtime.h>
#include <math.h>

#define BB 16
#define NN 4096
#define SS 512
#define KK 32
#define NPIX (BB*SS*KK)          /* 262144 pixels (b,s,k) */
#define NGRP (BB*SS)             /* 8192 groups */

static constexpr float R2F  = (float)0.16000000000000003;  // RADIUS**2 as f32
static constexpr float EPSF = 1e-5f;

// ---------------- workspace layout (bytes) ----------------
constexpr size_t OFF_NXYZ = 0;                     // B*S*3 f32  = 98304
constexpr size_t OFF_GRP  = 98304;                 // B*S*NS i32 = 1048576
constexpr size_t OFF_P1   = 98304 + 1048576;       // 2*64*32 f64  = 32768
constexpr size_t OFF_P2   = OFF_P1 + 32768;
constexpr size_t OFF_P3   = OFF_P2 + 32768;        // 2*128*32 f64 = 65536
constexpr size_t OFF_MR1  = OFF_P3 + 65536;        // 64*2 f32
constexpr size_t OFF_MR2  = OFF_MR1 + 512;
constexpr size_t OFF_MR3  = OFF_MR2 + 512;         // 128*2 f32
constexpr size_t OFF_Z3   = 2*1024*1024;
constexpr size_t Z3SZ     = (size_t)NPIX*128*4;    // 134217728
constexpr size_t OFF_Z2   = OFF_Z3 + Z3SZ;         // 136MB
constexpr size_t Z2SZ     = (size_t)NPIX*64*4;     // 67108864
constexpr size_t NEED_Z3  = OFF_Z3 + Z3SZ;         // ~136MB
constexpr size_t NEED_Z2  = OFF_Z2 + Z2SZ;         // ~203MB

// DPP wave64 reduction steps: row_shr:1,2,4,8 then row_bcast:15, row_bcast:31.
// Invalid lanes return `old` (= current value) -> no-op combine. Result lane 63.
#define DPP_FMAX(v, ctrl) { int _t = __builtin_amdgcn_update_dpp(              \
      __float_as_int(v), __float_as_int(v), ctrl, 0xf, 0xf, false);            \
      v = fmaxf(v, __int_as_float(_t)); }
#define DPP_UMIN(v, ctrl) { unsigned _t = (unsigned)__builtin_amdgcn_update_dpp( \
      (int)(v), (int)(v), ctrl, 0xf, 0xf, false);                              \
      v = (v < _t ? v : _t); }

// ======================= FPS =======================
// Round-7 change: 2 independent batches per block (8 blocks x 512 threads).
// Halves (t<256 / t>=256) run separate batches with separate LDS state and
// share only the per-step __syncthreads. Each SIMD now carries 2 waves from
// DIFFERENT batches -> one batch's serial latency (skey read, pt4[far] read,
// DPP dep chain) overlaps the other's 320-cycle distance-update issue phase.
// Reduction logic is byte-identical to the round-6 passing kernel.
__global__ __launch_bounds__(512) void fps_kernel(const float* __restrict__ xyz,
        float* __restrict__ out0, float* __restrict__ nxyz){
  const int t    = threadIdx.x;
  const int half = t >> 8;                 // 0/1: which batch of this block
  const int tt   = t & 255;
  const int b    = blockIdx.x*2 + half;
  const float* xb = xyz + (size_t)b*3*NN;
  __shared__ float4 pt4[2][NN];            // 128 KB
  __shared__ __align__(16) unsigned long long skey[2][2][4];  // [half][buf][wv]
  __shared__ int hist[2][SS];
  const int lane = t & 63;
  const int wv   = (t >> 6) & 3;           // wave index within half
  float rx[16], ry[16], rz[16], rd[16];
#pragma unroll
  for (int j=0;j<16;j++){
    int i = tt + 256*j;
    float x = xb[i], y = xb[NN+i], z = xb[2*NN+i];
    rx[j]=x; ry[j]=y; rz[j]=z;
    pt4[half][i] = make_float4(x,y,z,0.0f);
    rd[j]=1e10f;
  }
  __syncthreads();
  int far = 0;
  for (int s=0;s<SS;s++){
    const int buf = s & 1;
    float4 c = pt4[half][far];
    if (tt==0) hist[half][s] = far;
    float bv = -1.0f;
#pragma unroll
    for (int j=0;j<16;j++){
      float dx=__fsub_rn(rx[j],c.x), dy=__fsub_rn(ry[j],c.y), dz=__fsub_rn(rz[j],c.z);
      float d2=__fadd_rn(__fadd_rn(__fmul_rn(dx,dx),__fmul_rn(dy,dy)),__fmul_rn(dz,dz));
      float nd=fminf(rd[j],d2);
      rd[j]=nd;
      bv = fmaxf(bv, nd);
    }
    // wave max of bv (result in lane 63), broadcast via readlane
    DPP_FMAX(bv,0x111); DPP_FMAX(bv,0x112); DPP_FMAX(bv,0x114);
    DPP_FMAX(bv,0x118); DPP_FMAX(bv,0x142); DPP_FMAX(bv,0x143);
    const float vmax = __int_as_float(__builtin_amdgcn_readlane(__float_as_int(bv), 63));
    // lane-local lowest matching index (descending j: last write = lowest idx)
    unsigned cand = 0xFFFFFFFFu;
#pragma unroll
    for (int j=15;j>=0;j--) if (rd[j]==vmax) cand = (unsigned)(tt+256*j);
    // wave min of cand (result in lane 63)
    DPP_UMIN(cand,0x111); DPP_UMIN(cand,0x112); DPP_UMIN(cand,0x114);
    DPP_UMIN(cand,0x118); DPP_UMIN(cand,0x142); DPP_UMIN(cand,0x143);
    if (lane==63){
      skey[half][buf][wv] = ((unsigned long long)(unsigned)__float_as_int(vmax) << 32)
                          | (unsigned)(~cand);
    }
    __syncthreads();   // only lgkm traffic outstanding -> cheap drain
    unsigned long long k0=skey[half][buf][0], k1=skey[half][buf][1],
                       k2=skey[half][buf][2], k3=skey[half][buf][3];
    unsigned long long m01 = (k0>k1)?k0:k1, m23 = (k2>k3)?k2:k3;
    unsigned long long m   = (m01>m23)?m01:m23;
    far = (int)(~(unsigned)(m & 0xFFFFFFFFull));
    // no WAR barrier: skey[half][buf] rewritten at step s+2, past s+1's barrier
  }
  __syncthreads();
  // cooperative writeout (once)
  for (int s=tt;s<SS;s+=256){
    int idx = hist[half][s];
    float4 c = pt4[half][idx];
    int gid = b*SS + s;
    nxyz[gid*3+0]=c.x; nxyz[gid*3+1]=c.y; nxyz[gid*3+2]=c.z;
    out0[(b*3+0)*SS+s]=c.x; out0[(b*3+1)*SS+s]=c.y; out0[(b*3+2)*SS+s]=c.z;
  }
}

// ======================= ball query (unchanged, passing) =======================
__global__ __launch_bounds__(256) void ball_kernel(const float* __restrict__ xyz,
        const float* __restrict__ nxyz, int* __restrict__ grp){
  const int gw   = (blockIdx.x*256 + threadIdx.x) >> 6;
  const int lane = threadIdx.x & 63;
  if (gw >= NGRP) return;
  const int b = gw / SS;
  const float* xb = xyz + (size_t)b*3*NN;
  const float nx=nxyz[gw*3+0], ny=nxyz[gw*3+1], nz=nxyz[gw*3+2];
  const float sn = __fadd_rn(__fadd_rn(__fmul_rn(nx,nx),__fmul_rn(ny,ny)),__fmul_rn(nz,nz));
  int cnt=0, first=-1;
  int* g = grp + (size_t)gw*KK;
  for (int c=0;c<NN/64 && cnt<KK;c++){
    int i=c*64+lane;
    float x=xb[i], y=xb[NN+i], z=xb[2*NN+i];
    float sxx=__fadd_rn(__fadd_rn(__fmul_rn(x,x),__fmul_rn(y,y)),__fmul_rn(z,z));
    float dot=__fadd_rn(__fadd_rn(__fmul_rn(nx,x),__fmul_rn(ny,y)),__fmul_rn(nz,z));
    float sqr=__fsub_rn(__fadd_rn(sn,sxx),__fmul_rn(2.0f,dot));
    bool m = (sqr <= R2F);
    unsigned long long mask = __ballot(m);
    if (m){
      int pos = cnt + __popcll(mask & ((1ull<<lane)-1ull));
      if (pos < KK) g[pos] = i;
    }
    if (first<0 && mask) first = c*64 + (__ffsll((long long)mask) - 1);
    cnt += __popcll(mask);
  }
  if (cnt < KK && lane >= cnt && lane < KK) g[lane] = first;
}

// ======================= finalize (unchanged) =======================
__global__ void finalize_kernel(const double* __restrict__ part, float* __restrict__ mr, int C){
  int o = threadIdx.x;
  if (o < C){
    double s1=0.0, s2=0.0;
    for (int k=0;k<32;k++){ s1 += part[o*32+k]; s2 += part[(C+o)*32+k]; }
    const double n = (double)NPIX;
    double mean = s1/n;
    double var  = s2/n - mean*mean;
    mr[2*o]   = (float)mean;
    mr[2*o+1] = (float)(1.0/sqrt(var + (double)EPSF));
  }
}

// ======================= tiled MLP chain =======================
// Z2IO: stage 2 stores pre-norm z2 to ws; stage 3 loads it instead of
// recomputing L1+L2 (bit-identical values). Tiered on ws_size.
constexpr int XIN = 0;          // 6*68   = 408
constexpr int W0F = 408;        // 6*64   = 384
constexpr int B0F = 792;        // 64
constexpr int W1F = 856;        // 64*64  = 4096
constexpr int B1F = 4952;       // 64
constexpr int XBF = 5016;       // 64*68  = 4352
constexpr int SRF = 9368;       // 256  (f32 stats red, or u32 maxpool)
constexpr int W2F = 9624;       // 64*128 = 8192
constexpr int B2F = 17816;      // 128
constexpr int SM_SMALL = 9624;  // stages 1,2 (38.5 KB)
constexpr int SM_BIG   = 17944; // stages 3,4 (71.8 KB -> 2 blocks/CU)

template<int STAGE, bool STZ3, bool Z2IO>
__global__ __launch_bounds__(256,2) void mlp_kernel(
    const float* __restrict__ xyz, const float* __restrict__ pts,
    const float* __restrict__ nxyz, const int* __restrict__ grp,
    const float* __restrict__ w0, const float* __restrict__ b0,
    const float* __restrict__ mr1, const float* __restrict__ g0, const float* __restrict__ be0,
    const float* __restrict__ w1, const float* __restrict__ b1,
    const float* __restrict__ mr2, const float* __restrict__ g1, const float* __restrict__ be1,
    const float* __restrict__ w2, const float* __restrict__ b2,
    const float* __restrict__ mr3, const float* __restrict__ g2, const float* __restrict__ be2,
    double* __restrict__ part, float* __restrict__ out1,
    float* __restrict__ z2w, float* __restrict__ z3w)
{
  __shared__ float sm[(STAGE>=3)? SM_BIG : SM_SMALL];
  const int t   = threadIdx.x;
  const int blk = blockIdx.x;
  const int tx  = t & 15, ty = t >> 4;
  const int p0  = blk*64;
  const int slot = blk & 31;
  constexpr bool SKIP12 = (STAGE==3 && Z2IO);   // z2 sourced from global

  sm[SRF + t] = 0.0f;   // stats / maxpool slot (0.0f bits == 0u)

  if constexpr (!SKIP12){
    for (int i=t;i<384;i+=256){ int o=i/6, c=i-o*6; sm[W0F + c*64 + o] = w0[i]; }
    if (t<64) sm[B0F+t] = b0[t];
    if constexpr (STAGE>=2){
      for (int i=t;i<4096;i+=256){ int o=i&63, c=i>>6; sm[W1F + c*64 + o] = w1[o*64+c]; }
      if (t<64) sm[B1F+t] = b1[t];
    }
    for (int i=t;i<384;i+=256){
      int c=i>>6, px=i&63, p=p0+px, gid=p>>5, bb=p>>14;
      int idx = grp[p];
      float v;
      if (c<3) v = __fsub_rn(xyz[(size_t)bb*3*NN + c*NN + idx], nxyz[gid*3+c]);
      else     v = pts[(size_t)bb*3*NN + (c-3)*NN + idx];
      sm[XIN + c*68 + px] = v;
    }
  }
  if constexpr (STAGE>=3){
    for (int i=t;i<8192;i+=256){ int o=i&127, c=i>>7; sm[W2F + c*128 + o] = w2[o*64+c]; }
    if (t<128) sm[B2F+t] = b2[t];
  }
  __syncthreads();

  float z[4][4];
  if constexpr (SKIP12){
    // z2 (pre-norm) from global: same per-thread layout as the compute path
#pragma unroll
    for (int i=0;i<4;i++){
      float4 v = *(const float4*)&z2w[(size_t)(p0 + ty*4 + i)*64 + tx*4];
      z[i][0]=v.x; z[i][1]=v.y; z[i][2]=v.z; z[i][3]=v.w;
    }
  } else {
    // ---- layer 1: 6 -> 64 ----
#pragma unroll
    for (int i=0;i<4;i++)
#pragma unroll
      for (int j=0;j<4;j++) z[i][j]=0.0f;
#pragma unroll
    for (int k=0;k<6;k++){
      float4 xv = *(const float4*)&sm[XIN + k*68 + ty*4];
      float4 wv = *(const float4*)&sm[W0F + k*64 + tx*4];
      const float xs[4]={xv.x,xv.y,xv.z,xv.w};
      const float wsv[4]={wv.x,wv.y,wv.z,wv.w};
#pragma unroll
      for (int i=0;i<4;i++)
#pragma unroll
        for (int j=0;j<4;j++) z[i][j] = fmaf(xs[i], wsv[j], z[i][j]);
    }
#pragma unroll
    for (int i=0;i<4;i++)
#pragma unroll
      for (int j=0;j<4;j++) z[i][j] = __fadd_rn(z[i][j], sm[B0F + tx*4 + j]);

    if constexpr (STAGE==1){
#pragma unroll
      for (int j=0;j<4;j++){
        float s1=0.0f, s2=0.0f;
#pragma unroll
        for (int i=0;i<4;i++){ s1 = __fadd_rn(s1, z[i][j]); s2 = fmaf(z[i][j], z[i][j], s2); }
        atomicAdd(&sm[SRF + (tx*4+j)*2    ], s1);
        atomicAdd(&sm[SRF + (tx*4+j)*2 + 1], s2);
      }
      __syncthreads();
      if (t<128){ int ch=t>>1, m=t&1;
        atomicAdd(part + (size_t)((m? 64+ch : ch)*32 + slot), (double)sm[SRF+t]);
      }
      return;
    }

    // norm+relu(mr1) -> xbuf
#pragma unroll
    for (int j=0;j<4;j++){
      int ch = tx*4+j;
      float m=mr1[2*ch], r=mr1[2*ch+1], gg=g0[ch], bt=be0[ch];
      float4 o;
      o.x = fmaxf(fmaf(__fmul_rn(__fsub_rn(z[0][j],m),r), gg, bt), 0.0f);
      o.y = fmaxf(fmaf(__fmul_rn(__fsub_rn(z[1][j],m),r), gg, bt), 0.0f);
      o.z = fmaxf(fmaf(__fmul_rn(__fsub_rn(z[2][j],m),r), gg, bt), 0.0f);
      o.w = fmaxf(fmaf(__fmul_rn(__fsub_rn(z[3][j],m),r), gg, bt), 0.0f);
      *(float4*)&sm[XBF + ch*68 + ty*4] = o;
    }
    __syncthreads();

    // ---- layer 2: 64 -> 64 ----
#pragma unroll
    for (int i=0;i<4;i++)
#pragma unroll
      for (int j=0;j<4;j++) z[i][j]=0.0f;
#pragma unroll 8
    for (int k=0;k<64;k++){
      float4 xv = *(const float4*)&sm[XBF + k*68 + ty*4];
      float4 wv = *(const float4*)&sm[W1F + k*64 + tx*4];
      const float xs[4]={xv.x,xv.y,xv.z,xv.w};
      const float wsv[4]={wv.x,wv.y,wv.z,wv.w};
#pragma unroll
      for (int i=0;i<4;i++)
#pragma unroll
        for (int j=0;j<4;j++) z[i][j] = fmaf(xs[i], wsv[j], z[i][j]);
    }
#pragma unroll
    for (int i=0;i<4;i++)
#pragma unroll
      for (int j=0;j<4;j++) z[i][j] = __fadd_rn(z[i][j], sm[B1F + tx*4 + j]);

    if constexpr (STAGE==2){
      if constexpr (Z2IO){
#pragma unroll
        for (int i=0;i<4;i++)
          *(float4*)&z2w[(size_t)(p0 + ty*4 + i)*64 + tx*4]
              = make_float4(z[i][0], z[i][1], z[i][2], z[i][3]);
      }
#pragma unroll
      for (int j=0;j<4;j++){
        float s1=0.0f, s2=0.0f;
#pragma unroll
        for (int i=0;i<4;i++){ s1 = __fadd_rn(s1, z[i][j]); s2 = fmaf(z[i][j], z[i][j], s2); }
        atomicAdd(&sm[SRF + (tx*4+j)*2    ], s1);
        atomicAdd(&sm[SRF + (tx*4+j)*2 + 1], s2);
      }
      __syncthreads();
      if (t<128){ int ch=t>>1, m=t&1;
        atomicAdd(part + (size_t)((m? 64+ch : ch)*32 + slot), (double)sm[SRF+t]);
      }
      return;
    }
  }

  if constexpr (STAGE>=3){
    __syncthreads();   // WAR guard on XBF (no-op ordering cost in SKIP12 path)
#pragma unroll
    for (int j=0;j<4;j++){
      int ch = tx*4+j;
      float m=mr2[2*ch], r=mr2[2*ch+1], gg=g1[ch], bt=be1[ch];
      float4 o;
      o.x = fmaxf(fmaf(__fmul_rn(__fsub_rn(z[0][j],m),r), gg, bt), 0.0f);
      o.y = fmaxf(fmaf(__fmul_rn(__fsub_rn(z[1][j],m),r), gg, bt), 0.0f);
      o.z = fmaxf(fmaf(__fmul_rn(__fsub_rn(z[2][j],m),r), gg, bt), 0.0f);
      o.w = fmaxf(fmaf(__fmul_rn(__fsub_rn(z[3][j],m),r), gg, bt), 0.0f);
      *(float4*)&sm[XBF + ch*68 + ty*4] = o;
    }
    __syncthreads();

    // ---- layer 3: 64 -> 128 ----
    float a3[4][8];
#pragma unroll
    for (int i=0;i<4;i++)
#pragma unroll
      for (int j=0;j<8;j++) a3[i][j]=0.0f;
#pragma unroll 4
    for (int k=0;k<64;k++){
      float4 xv  = *(const float4*)&sm[XBF + k*68  + ty*4];
      float4 wv0 = *(const float4*)&sm[W2F + k*128 + tx*4];
      float4 wv1 = *(const float4*)&sm[W2F + k*128 + 64 + tx*4];
      const float xs[4]={xv.x,xv.y,xv.z,xv.w};
      const float wsv[8]={wv0.x,wv0.y,wv0.z,wv0.w, wv1.x,wv1.y,wv1.z,wv1.w};
#pragma unroll
      for (int i=0;i<4;i++)
#pragma unroll
        for (int j=0;j<8;j++) a3[i][j] = fmaf(xs[i], wsv[j], a3[i][j]);
    }
#pragma unroll
    for (int i=0;i<4;i++)
#pragma unroll
      for (int j=0;j<8;j++){
        int ch = (j<4)? (tx*4+j) : (64+tx*4+(j-4));
        a3[i][j] = __fadd_rn(a3[i][j], sm[B2F + ch]);
      }

    if constexpr (STAGE==3){
      if constexpr (STZ3){
#pragma unroll
        for (int i=0;i<4;i++){
          size_t p = (size_t)(p0 + ty*4 + i)*128;
          *(float4*)&z3w[p + tx*4]      = make_float4(a3[i][0],a3[i][1],a3[i][2],a3[i][3]);
          *(float4*)&z3w[p + 64 + tx*4] = make_float4(a3[i][4],a3[i][5],a3[i][6],a3[i][7]);
        }
      }
#pragma unroll
      for (int j=0;j<8;j++){
        int ch = (j<4)? (tx*4+j) : (64+tx*4+(j-4));
        float s1=0.0f, s2=0.0f;
#pragma unroll
        for (int i=0;i<4;i++){ s1 = __fadd_rn(s1, a3[i][j]); s2 = fmaf(a3[i][j], a3[i][j], s2); }
        atomicAdd(&sm[SRF + ch*2    ], s1);
        atomicAdd(&sm[SRF + ch*2 + 1], s2);
      }
      __syncthreads();
      { int ch=t>>1, m=t&1;
        atomicAdd(part + (size_t)((m? 128+ch : ch)*32 + slot), (double)sm[SRF+t]);
      }
      return;
    }

    if constexpr (STAGE==4){
      const int grp_l = ty>>3;
      unsigned* omax = (unsigned*)sm;
#pragma unroll
      for (int j=0;j<8;j++){
        int ch = (j<4)? (tx*4+j) : (64+tx*4+(j-4));
        float m=mr3[2*ch], r=mr3[2*ch+1], gg=g2[ch], bt=be2[ch];
        float vmax=0.0f;
#pragma unroll
        for (int i=0;i<4;i++){
          float v = fmaxf(fmaf(__fmul_rn(__fsub_rn(a3[i][j],m),r), gg, bt), 0.0f);
          vmax = fmaxf(vmax, v);
        }
        atomicMax(&omax[SRF + grp_l*128 + ch], __float_as_uint(vmax));
      }
      __syncthreads();
      { int g = t>>7, o = t&127;
        int gid = blk*2 + g, bb = gid>>9, s = gid&511;
        out1[((size_t)(bb*128+o))*512 + s] = __uint_as_float(omax[SRF + t]);
      }
    }
  }
}

// ======================= maxpool reader (unchanged, passing) =======================
__global__ __launch_bounds__(256) void maxpool_kernel(const float* __restrict__ z3,
        const float* __restrict__ mr3, const float* __restrict__ g2,
        const float* __restrict__ be2, float* __restrict__ out1){
  const int t = threadIdx.x;
  const int g = blockIdx.x*2 + (t>>7);     // group id (b*SS+s)
  const int o = t & 127;
  const int bb = g >> 9, s = g & 511;
  const float* zp = z3 + (size_t)g*KK*128 + o;
  float m=mr3[2*o], r=mr3[2*o+1], gg=g2[o], bt=be2[o];
  float mx = 0.0f;                         // relu outputs are >= 0
#pragma unroll 8
  for (int k=0;k<KK;k++){
    float v = fmaxf(fmaf(__fmul_rn(__fsub_rn(zp[(size_t)k*128],m),r), gg, bt), 0.0f);
    mx = fmaxf(mx, v);
  }
  out1[((size_t)(bb*128+o))*SS + s] = mx;
}

// ======================= launch =======================
extern "C" void kernel_launch(void* const* d_in, const int* in_sizes, int n_in,
                              void* d_out, int out_size, void* d_ws, size_t ws_size,
                              hipStream_t stream){
  const float* xyz = (const float*)d_in[0];
  const float* pts = (const float*)d_in[1];
  const float* w0  = (const float*)d_in[2];  const float* b0  = (const float*)d_in[3];
  const float* g0  = (const float*)d_in[4];  const float* be0 = (const float*)d_in[5];
  const float* w1  = (const float*)d_in[6];  const float* b1  = (const float*)d_in[7];
  const float* g1  = (const float*)d_in[8];  const float* be1 = (const float*)d_in[9];
  const float* w2  = (const float*)d_in[10]; const float* b2  = (const float*)d_in[11];
  const float* g2  = (const float*)d_in[12]; const float* be2 = (const float*)d_in[13];

  float* out  = (float*)d_out;
  float* out1 = out + BB*3*SS;
  char*  ws   = (char*)d_ws;

  float*  nxyz = (float*)(ws + OFF_NXYZ);
  int*    grp  = (int*)  (ws + OFF_GRP);
  double* p1   = (double*)(ws + OFF_P1);
  double* p2   = (double*)(ws + OFF_P2);
  double* p3   = (double*)(ws + OFF_P3);
  float*  mr1  = (float*)(ws + OFF_MR1);
  float*  mr2  = (float*)(ws + OFF_MR2);
  float*  mr3  = (float*)(ws + OFF_MR3);
  float*  z3w  = (float*)(ws + OFF_Z3);
  float*  z2w  = (float*)(ws + OFF_Z2);

  const bool stz3 = (ws_size >= NEED_Z3);
  const bool stz2 = (ws_size >= NEED_Z2);   // implies stz3

  hipMemsetAsync(ws + OFF_P1, 0, 32768+32768+65536, stream);

  fps_kernel <<<BB/2, 512, 0, stream>>>(xyz, out, nxyz);
  ball_kernel<<<NGRP*64/256, 256, 0, stream>>>(xyz, nxyz, grp);

#define MLP_ARGS xyz, pts, nxyz, grp, w0, b0, mr1, g0, be0, w1, b1, mr2, g1, be1, w2, b2, mr3, g2, be2
  mlp_kernel<1,false,false><<<NPIX/64, 256, 0, stream>>>(MLP_ARGS, p1, out1, z2w, z3w);
  finalize_kernel<<<1,128,0,stream>>>(p1, mr1, 64);
  if (stz2) mlp_kernel<2,false,true ><<<NPIX/64, 256, 0, stream>>>(MLP_ARGS, p2, out1, z2w, z3w);
  else      mlp_kernel<2,false,false><<<NPIX/64, 256, 0, stream>>>(MLP_ARGS, p2, out1, z2w, z3w);
  finalize_kernel<<<1,128,0,stream>>>(p2, mr2, 64);
  if (stz2)      mlp_kernel<3,true ,true ><<<NPIX/64, 256, 0, stream>>>(MLP_ARGS, p3, out1, z2w, z3w);
  else if (stz3) mlp_kernel<3,true ,false><<<NPIX/64, 256, 0, stream>>>(MLP_ARGS, p3, out1, z2w, z3w);
  else           mlp_kernel<3,false,false><<<NPIX/64, 256, 0, stream>>>(MLP_ARGS, p3, out1, z2w, z3w);
  finalize_kernel<<<1,128,0,stream>>>(p3, mr3, 128);
  if (stz3) maxpool_kernel<<<NGRP/2, 256, 0, stream>>>(z3w, mr3, g2, be2, out1);
  else      mlp_kernel<4,false,false><<<NPIX/64, 256, 0, stream>>>(MLP_ARGS, p3, out1, z2w, z3w);
#undef MLP_ARGS
}

// Round 9
// 798.721 us; speedup vs baseline: 1.1442x; 1.1442x over previous
//
#include <hip/hip_runtime.h>
#include <math.h>

#define BB 16
#define NN 4096
#define SS 512
#define KK 32
#define NPIX (BB*SS*KK)          /* 262144 pixels (b,s,k) */
#define NGRP (BB*SS)             /* 8192 groups */

static constexpr float R2F  = (float)0.16000000000000003;  // RADIUS**2 as f32
static constexpr float EPSF = 1e-5f;

// ---------------- workspace layout (bytes) ----------------
constexpr size_t OFF_NXYZ = 0;                     // B*S*3 f32  = 98304
constexpr size_t OFF_GRP  = 98304;                 // B*S*NS i32 = 1048576
constexpr size_t OFF_P1   = 98304 + 1048576;       // 2*64*32 f64  = 32768
constexpr size_t OFF_P2   = OFF_P1 + 32768;
constexpr size_t OFF_P3   = OFF_P2 + 32768;        // 2*128*32 f64 = 65536
constexpr size_t OFF_MR1  = OFF_P3 + 65536;        // 64*2 f32
constexpr size_t OFF_MR2  = OFF_MR1 + 512;
constexpr size_t OFF_MR3  = OFF_MR2 + 512;         // 128*2 f32
constexpr size_t OFF_Z3   = 2*1024*1024;
constexpr size_t Z3SZ     = (size_t)NPIX*128*4;    // 134217728
constexpr size_t OFF_Z2   = OFF_Z3 + Z3SZ;         // 136MB
constexpr size_t Z2SZ     = (size_t)NPIX*64*4;     // 67108864
constexpr size_t NEED_Z3  = OFF_Z3 + Z3SZ;         // ~136MB
constexpr size_t NEED_Z2  = OFF_Z2 + Z2SZ;         // ~203MB

// DPP wave64 reduction steps: row_shr:1,2,4,8 then row_bcast:15, row_bcast:31.
// Invalid lanes return `old` (= current value) -> no-op combine. Result lane 63.
#define DPP_FMAX(v, ctrl) { int _t = __builtin_amdgcn_update_dpp(              \
      __float_as_int(v), __float_as_int(v), ctrl, 0xf, 0xf, false);            \
      v = fmaxf(v, __int_as_float(_t)); }
#define DPP_UMIN(v, ctrl) { unsigned _t = (unsigned)__builtin_amdgcn_update_dpp( \
      (int)(v), (int)(v), ctrl, 0xf, 0xf, false);                              \
      v = (v < _t ? v : _t); }

// ======================= FPS =======================
// Round-8 (re-land): single batch per block (r7's 2-batch shared-barrier
// phase-lock REVERTED), 512 threads / 8 waves / 8 pts per thread, DPP
// reduction (r6's verified logic). Rationale: per-step time = issue +
// serial latency; DPP already removed the bpermute chain, so halving
// per-wave issue (160 vs 320 cyc dist loop) shortens the critical path;
// latency path is unchanged.
__global__ __launch_bounds__(512) void fps_kernel(const float* __restrict__ xyz,
        float* __restrict__ out0, float* __restrict__ nxyz){
  const int b = blockIdx.x;
  const float* xb = xyz + (size_t)b*3*NN;
  __shared__ float4 pt4[NN];                       // 64 KB
  __shared__ __align__(16) unsigned long long skey[2][8];
  __shared__ int hist[SS];
  const int t = threadIdx.x;
  const int lane = t & 63, wv = t >> 6;            // wv in [0,8)
  float rx[8], ry[8], rz[8], rd[8];
#pragma unroll
  for (int j=0;j<8;j++){
    int i = t + 512*j;
    float x = xb[i], y = xb[NN+i], z = xb[2*NN+i];
    rx[j]=x; ry[j]=y; rz[j]=z;
    pt4[i] = make_float4(x,y,z,0.0f);
    rd[j]=1e10f;
  }
  __syncthreads();
  int far = 0;
  for (int s=0;s<SS;s++){
    const int buf = s & 1;
    float4 c = pt4[far];
    if (t==0) hist[s] = far;
    float bv = -1.0f;
#pragma unroll
    for (int j=0;j<8;j++){
      float dx=__fsub_rn(rx[j],c.x), dy=__fsub_rn(ry[j],c.y), dz=__fsub_rn(rz[j],c.z);
      float d2=__fadd_rn(__fadd_rn(__fmul_rn(dx,dx),__fmul_rn(dy,dy)),__fmul_rn(dz,dz));
      float nd=fminf(rd[j],d2);
      rd[j]=nd;
      bv = fmaxf(bv, nd);
    }
    // wave max of bv (result in lane 63), broadcast via readlane
    DPP_FMAX(bv,0x111); DPP_FMAX(bv,0x112); DPP_FMAX(bv,0x114);
    DPP_FMAX(bv,0x118); DPP_FMAX(bv,0x142); DPP_FMAX(bv,0x143);
    const float vmax = __int_as_float(__builtin_amdgcn_readlane(__float_as_int(bv), 63));
    // lane-local lowest matching index (descending j: last write = lowest idx)
    unsigned cand = 0xFFFFFFFFu;
#pragma unroll
    for (int j=7;j>=0;j--) if (rd[j]==vmax) cand = (unsigned)(t+512*j);
    // wave min of cand (result in lane 63)
    DPP_UMIN(cand,0x111); DPP_UMIN(cand,0x112); DPP_UMIN(cand,0x114);
    DPP_UMIN(cand,0x118); DPP_UMIN(cand,0x142); DPP_UMIN(cand,0x143);
    if (lane==63){
      skey[buf][wv] = ((unsigned long long)(unsigned)__float_as_int(vmax) << 32)
                    | (unsigned)(~cand);
    }
    __syncthreads();   // only lgkm traffic outstanding -> cheap drain
    unsigned long long k0=skey[buf][0], k1=skey[buf][1], k2=skey[buf][2], k3=skey[buf][3];
    unsigned long long k4=skey[buf][4], k5=skey[buf][5], k6=skey[buf][6], k7=skey[buf][7];
    unsigned long long m01=(k0>k1)?k0:k1, m23=(k2>k3)?k2:k3;
    unsigned long long m45=(k4>k5)?k4:k5, m67=(k6>k7)?k6:k7;
    unsigned long long mA=(m01>m23)?m01:m23, mB=(m45>m67)?m45:m67;
    unsigned long long m =(mA>mB)?mA:mB;
    far = (int)(~(unsigned)(m & 0xFFFFFFFFull));
    // no WAR barrier: skey[buf] rewritten at step s+2, after step s+1's barrier
  }
  __syncthreads();
  // cooperative writeout (once); SS == 512 == blockDim
  {
    int idx = hist[t];
    float4 c = pt4[idx];
    int gid = b*SS + t;
    nxyz[gid*3+0]=c.x; nxyz[gid*3+1]=c.y; nxyz[gid*3+2]=c.z;
    out0[(b*3+0)*SS+t]=c.x; out0[(b*3+1)*SS+t]=c.y; out0[(b*3+2)*SS+t]=c.z;
  }
}

// ======================= ball query (unchanged, passing) =======================
__global__ __launch_bounds__(256) void ball_kernel(const float* __restrict__ xyz,
        const float* __restrict__ nxyz, int* __restrict__ grp){
  const int gw   = (blockIdx.x*256 + threadIdx.x) >> 6;
  const int lane = threadIdx.x & 63;
  if (gw >= NGRP) return;
  const int b = gw / SS;
  const float* xb = xyz + (size_t)b*3*NN;
  const float nx=nxyz[gw*3+0], ny=nxyz[gw*3+1], nz=nxyz[gw*3+2];
  const float sn = __fadd_rn(__fadd_rn(__fmul_rn(nx,nx),__fmul_rn(ny,ny)),__fmul_rn(nz,nz));
  int cnt=0, first=-1;
  int* g = grp + (size_t)gw*KK;
  for (int c=0;c<NN/64 && cnt<KK;c++){
    int i=c*64+lane;
    float x=xb[i], y=xb[NN+i], z=xb[2*NN+i];
    float sxx=__fadd_rn(__fadd_rn(__fmul_rn(x,x),__fmul_rn(y,y)),__fmul_rn(z,z));
    float dot=__fadd_rn(__fadd_rn(__fmul_rn(nx,x),__fmul_rn(ny,y)),__fmul_rn(nz,z));
    float sqr=__fsub_rn(__fadd_rn(sn,sxx),__fmul_rn(2.0f,dot));
    bool m = (sqr <= R2F);
    unsigned long long mask = __ballot(m);
    if (m){
      int pos = cnt + __popcll(mask & ((1ull<<lane)-1ull));
      if (pos < KK) g[pos] = i;
    }
    if (first<0 && mask) first = c*64 + (__ffsll((long long)mask) - 1);
    cnt += __popcll(mask);
  }
  if (cnt < KK && lane >= cnt && lane < KK) g[lane] = first;
}

// ======================= finalize (unchanged) =======================
__global__ void finalize_kernel(const double* __restrict__ part, float* __restrict__ mr, int C){
  int o = threadIdx.x;
  if (o < C){
    double s1=0.0, s2=0.0;
    for (int k=0;k<32;k++){ s1 += part[o*32+k]; s2 += part[(C+o)*32+k]; }
    const double n = (double)NPIX;
    double mean = s1/n;
    double var  = s2/n - mean*mean;
    mr[2*o]   = (float)mean;
    mr[2*o+1] = (float)(1.0/sqrt(var + (double)EPSF));
  }
}

// ======================= tiled MLP chain (unchanged from r7, passing) =======================
constexpr int XIN = 0;          // 6*68   = 408
constexpr int W0F = 408;        // 6*64   = 384
constexpr int B0F = 792;        // 64
constexpr int W1F = 856;        // 64*64  = 4096
constexpr int B1F = 4952;       // 64
constexpr int XBF = 5016;       // 64*68  = 4352
constexpr int SRF = 9368;       // 256  (f32 stats red, or u32 maxpool)
constexpr int W2F = 9624;       // 64*128 = 8192
constexpr int B2F = 17816;      // 128
constexpr int SM_SMALL = 9624;  // stages 1,2 (38.5 KB)
constexpr int SM_BIG   = 17944; // stages 3,4 (71.8 KB -> 2 blocks/CU)

template<int STAGE, bool STZ3, bool Z2IO>
__global__ __launch_bounds__(256,2) void mlp_kernel(
    const float* __restrict__ xyz, const float* __restrict__ pts,
    const float* __restrict__ nxyz, const int* __restrict__ grp,
    const float* __restrict__ w0, const float* __restrict__ b0,
    const float* __restrict__ mr1, const float* __restrict__ g0, const float* __restrict__ be0,
    const float* __restrict__ w1, const float* __restrict__ b1,
    const float* __restrict__ mr2, const float* __restrict__ g1, const float* __restrict__ be1,
    const float* __restrict__ w2, const float* __restrict__ b2,
    const float* __restrict__ mr3, const float* __restrict__ g2, const float* __restrict__ be2,
    double* __restrict__ part, float* __restrict__ out1,
    float* __restrict__ z2w, float* __restrict__ z3w)
{
  __shared__ float sm[(STAGE>=3)? SM_BIG : SM_SMALL];
  const int t   = threadIdx.x;
  const int blk = blockIdx.x;
  const int tx  = t & 15, ty = t >> 4;
  const int p0  = blk*64;
  const int slot = blk & 31;
  constexpr bool SKIP12 = (STAGE==3 && Z2IO);   // z2 sourced from global

  sm[SRF + t] = 0.0f;   // stats / maxpool slot (0.0f bits == 0u)

  if constexpr (!SKIP12){
    for (int i=t;i<384;i+=256){ int o=i/6, c=i-o*6; sm[W0F + c*64 + o] = w0[i]; }
    if (t<64) sm[B0F+t] = b0[t];
    if constexpr (STAGE>=2){
      for (int i=t;i<4096;i+=256){ int o=i&63, c=i>>6; sm[W1F + c*64 + o] = w1[o*64+c]; }
      if (t<64) sm[B1F+t] = b1[t];
    }
    for (int i=t;i<384;i+=256){
      int c=i>>6, px=i&63, p=p0+px, gid=p>>5, bb=p>>14;
      int idx = grp[p];
      float v;
      if (c<3) v = __fsub_rn(xyz[(size_t)bb*3*NN + c*NN + idx], nxyz[gid*3+c]);
      else     v = pts[(size_t)bb*3*NN + (c-3)*NN + idx];
      sm[XIN + c*68 + px] = v;
    }
  }
  if constexpr (STAGE>=3){
    for (int i=t;i<8192;i+=256){ int o=i&127, c=i>>7; sm[W2F + c*128 + o] = w2[o*64+c]; }
    if (t<128) sm[B2F+t] = b2[t];
  }
  __syncthreads();

  float z[4][4];
  if constexpr (SKIP12){
    // z2 (pre-norm) from global: same per-thread layout as the compute path
#pragma unroll
    for (int i=0;i<4;i++){
      float4 v = *(const float4*)&z2w[(size_t)(p0 + ty*4 + i)*64 + tx*4];
      z[i][0]=v.x; z[i][1]=v.y; z[i][2]=v.z; z[i][3]=v.w;
    }
  } else {
    // ---- layer 1: 6 -> 64 ----
#pragma unroll
    for (int i=0;i<4;i++)
#pragma unroll
      for (int j=0;j<4;j++) z[i][j]=0.0f;
#pragma unroll
    for (int k=0;k<6;k++){
      float4 xv = *(const float4*)&sm[XIN + k*68 + ty*4];
      float4 wv = *(const float4*)&sm[W0F + k*64 + tx*4];
      const float xs[4]={xv.x,xv.y,xv.z,xv.w};
      const float wsv[4]={wv.x,wv.y,wv.z,wv.w};
#pragma unroll
      for (int i=0;i<4;i++)
#pragma unroll
        for (int j=0;j<4;j++) z[i][j] = fmaf(xs[i], wsv[j], z[i][j]);
    }
#pragma unroll
    for (int i=0;i<4;i++)
#pragma unroll
      for (int j=0;j<4;j++) z[i][j] = __fadd_rn(z[i][j], sm[B0F + tx*4 + j]);

    if constexpr (STAGE==1){
#pragma unroll
      for (int j=0;j<4;j++){
        float s1=0.0f, s2=0.0f;
#pragma unroll
        for (int i=0;i<4;i++){ s1 = __fadd_rn(s1, z[i][j]); s2 = fmaf(z[i][j], z[i][j], s2); }
        atomicAdd(&sm[SRF + (tx*4+j)*2    ], s1);
        atomicAdd(&sm[SRF + (tx*4+j)*2 + 1], s2);
      }
      __syncthreads();
      if (t<128){ int ch=t>>1, m=t&1;
        atomicAdd(part + (size_t)((m? 64+ch : ch)*32 + slot), (double)sm[SRF+t]);
      }
      return;
    }

    // norm+relu(mr1) -> xbuf
#pragma unroll
    for (int j=0;j<4;j++){
      int ch = tx*4+j;
      float m=mr1[2*ch], r=mr1[2*ch+1], gg=g0[ch], bt=be0[ch];
      float4 o;
      o.x = fmaxf(fmaf(__fmul_rn(__fsub_rn(z[0][j],m),r), gg, bt), 0.0f);
      o.y = fmaxf(fmaf(__fmul_rn(__fsub_rn(z[1][j],m),r), gg, bt), 0.0f);
      o.z = fmaxf(fmaf(__fmul_rn(__fsub_rn(z[2][j],m),r), gg, bt), 0.0f);
      o.w = fmaxf(fmaf(__fmul_rn(__fsub_rn(z[3][j],m),r), gg, bt), 0.0f);
      *(float4*)&sm[XBF + ch*68 + ty*4] = o;
    }
    __syncthreads();

    // ---- layer 2: 64 -> 64 ----
#pragma unroll
    for (int i=0;i<4;i++)
#pragma unroll
      for (int j=0;j<4;j++) z[i][j]=0.0f;
#pragma unroll 8
    for (int k=0;k<64;k++){
      float4 xv = *(const float4*)&sm[XBF + k*68 + ty*4];
      float4 wv = *(const float4*)&sm[W1F + k*64 + tx*4];
      const float xs[4]={xv.x,xv.y,xv.z,xv.w};
      const float wsv[4]={wv.x,wv.y,wv.z,wv.w};
#pragma unroll
      for (int i=0;i<4;i++)
#pragma unroll
        for (int j=0;j<4;j++) z[i][j] = fmaf(xs[i], wsv[j], z[i][j]);
    }
#pragma unroll
    for (int i=0;i<4;i++)
#pragma unroll
      for (int j=0;j<4;j++) z[i][j] = __fadd_rn(z[i][j], sm[B1F + tx*4 + j]);

    if constexpr (STAGE==2){
      if constexpr (Z2IO){
#pragma unroll
        for (int i=0;i<4;i++)
          *(float4*)&z2w[(size_t)(p0 + ty*4 + i)*64 + tx*4]
              = make_float4(z[i][0], z[i][1], z[i][2], z[i][3]);
      }
#pragma unroll
      for (int j=0;j<4;j++){
        float s1=0.0f, s2=0.0f;
#pragma unroll
        for (int i=0;i<4;i++){ s1 = __fadd_rn(s1, z[i][j]); s2 = fmaf(z[i][j], z[i][j], s2); }
        atomicAdd(&sm[SRF + (tx*4+j)*2    ], s1);
        atomicAdd(&sm[SRF + (tx*4+j)*2 + 1], s2);
      }
      __syncthreads();
      if (t<128){ int ch=t>>1, m=t&1;
        atomicAdd(part + (size_t)((m? 64+ch : ch)*32 + slot), (double)sm[SRF+t]);
      }
      return;
    }
  }

  if constexpr (STAGE>=3){
    __syncthreads();   // WAR guard on XBF (harmless in SKIP12 path)
#pragma unroll
    for (int j=0;j<4;j++){
      int ch = tx*4+j;
      float m=mr2[2*ch], r=mr2[2*ch+1], gg=g1[ch], bt=be1[ch];
      float4 o;
      o.x = fmaxf(fmaf(__fmul_rn(__fsub_rn(z[0][j],m),r), gg, bt), 0.0f);
      o.y = fmaxf(fmaf(__fmul_rn(__fsub_rn(z[1][j],m),r), gg, bt), 0.0f);
      o.z = fmaxf(fmaf(__fmul_rn(__fsub_rn(z[2][j],m),r), gg, bt), 0.0f);
      o.w = fmaxf(fmaf(__fmul_rn(__fsub_rn(z[3][j],m),r), gg, bt), 0.0f);
      *(float4*)&sm[XBF + ch*68 + ty*4] = o;
    }
    __syncthreads();

    // ---- layer 3: 64 -> 128 ----
    float a3[4][8];
#pragma unroll
    for (int i=0;i<4;i++)
#pragma unroll
      for (int j=0;j<8;j++) a3[i][j]=0.0f;
#pragma unroll 4
    for (int k=0;k<64;k++){
      float4 xv  = *(const float4*)&sm[XBF + k*68  + ty*4];
      float4 wv0 = *(const float4*)&sm[W2F + k*128 + tx*4];
      float4 wv1 = *(const float4*)&sm[W2F + k*128 + 64 + tx*4];
      const float xs[4]={xv.x,xv.y,xv.z,xv.w};
      const float wsv[8]={wv0.x,wv0.y,wv0.z,wv0.w, wv1.x,wv1.y,wv1.z,wv1.w};
#pragma unroll
      for (int i=0;i<4;i++)
#pragma unroll
        for (int j=0;j<8;j++) a3[i][j] = fmaf(xs[i], wsv[j], a3[i][j]);
    }
#pragma unroll
    for (int i=0;i<4;i++)
#pragma unroll
      for (int j=0;j<8;j++){
        int ch = (j<4)? (tx*4+j) : (64+tx*4+(j-4));
        a3[i][j] = __fadd_rn(a3[i][j], sm[B2F + ch]);
      }

    if constexpr (STAGE==3){
      if constexpr (STZ3){
#pragma unroll
        for (int i=0;i<4;i++){
          size_t p = (size_t)(p0 + ty*4 + i)*128;
          *(float4*)&z3w[p + tx*4]      = make_float4(a3[i][0],a3[i][1],a3[i][2],a3[i][3]);
          *(float4*)&z3w[p + 64 + tx*4] = make_float4(a3[i][4],a3[i][5],a3[i][6],a3[i][7]);
        }
      }
#pragma unroll
      for (int j=0;j<8;j++){
        int ch = (j<4)? (tx*4+j) : (64+tx*4+(j-4));
        float s1=0.0f, s2=0.0f;
#pragma unroll
        for (int i=0;i<4;i++){ s1 = __fadd_rn(s1, a3[i][j]); s2 = fmaf(a3[i][j], a3[i][j], s2); }
        atomicAdd(&sm[SRF + ch*2    ], s1);
        atomicAdd(&sm[SRF + ch*2 + 1], s2);
      }
      __syncthreads();
      { int ch=t>>1, m=t&1;
        atomicAdd(part + (size_t)((m? 128+ch : ch)*32 + slot), (double)sm[SRF+t]);
      }
      return;
    }

    if constexpr (STAGE==4){
      const int grp_l = ty>>3;
      unsigned* omax = (unsigned*)sm;
#pragma unroll
      for (int j=0;j<8;j++){
        int ch = (j<4)? (tx*4+j) : (64+tx*4+(j-4));
        float m=mr3[2*ch], r=mr3[2*ch+1], gg=g2[ch], bt=be2[ch];
        float vmax=0.0f;
#pragma unroll
        for (int i=0;i<4;i++){
          float v = fmaxf(fmaf(__fmul_rn(__fsub_rn(a3[i][j],m),r), gg, bt), 0.0f);
          vmax = fmaxf(vmax, v);
        }
        atomicMax(&omax[SRF + grp_l*128 + ch], __float_as_uint(vmax));
      }
      __syncthreads();
      { int g = t>>7, o = t&127;
        int gid = blk*2 + g, bb = gid>>9, s = gid&511;
        out1[((size_t)(bb*128+o))*512 + s] = __uint_as_float(omax[SRF + t]);
      }
    }
  }
}

// ======================= maxpool reader (unchanged, passing) =======================
__global__ __launch_bounds__(256) void maxpool_kernel(const float* __restrict__ z3,
        const float* __restrict__ mr3, const float* __restrict__ g2,
        const float* __restrict__ be2, float* __restrict__ out1){
  const int t = threadIdx.x;
  const int g = blockIdx.x*2 + (t>>7);     // group id (b*SS+s)
  const int o = t & 127;
  const int bb = g >> 9, s = g & 511;
  const float* zp = z3 + (size_t)g*KK*128 + o;
  float m=mr3[2*o], r=mr3[2*o+1], gg=g2[o], bt=be2[o];
  float mx = 0.0f;                         // relu outputs are >= 0
#pragma unroll 8
  for (int k=0;k<KK;k++){
    float v = fmaxf(fmaf(__fmul_rn(__fsub_rn(zp[(size_t)k*128],m),r), gg, bt), 0.0f);
    mx = fmaxf(mx, v);
  }
  out1[((size_t)(bb*128+o))*SS + s] = mx;
}

// ======================= launch =======================
extern "C" void kernel_launch(void* const* d_in, const int* in_sizes, int n_in,
                              void* d_out, int out_size, void* d_ws, size_t ws_size,
                              hipStream_t stream){
  const float* xyz = (const float*)d_in[0];
  const float* pts = (const float*)d_in[1];
  const float* w0  = (const float*)d_in[2];  const float* b0  = (const float*)d_in[3];
  const float* g0  = (const float*)d_in[4];  const float* be0 = (const float*)d_in[5];
  const float* w1  = (const float*)d_in[6];  const float* b1  = (const float*)d_in[7];
  const float* g1  = (const float*)d_in[8];  const float* be1 = (const float*)d_in[9];
  const float* w2  = (const float*)d_in[10]; const float* b2  = (const float*)d_in[11];
  const float* g2  = (const float*)d_in[12]; const float* be2 = (const float*)d_in[13];

  float* out  = (float*)d_out;
  float* out1 = out + BB*3*SS;
  char*  ws   = (char*)d_ws;

  float*  nxyz = (float*)(ws + OFF_NXYZ);
  int*    grp  = (int*)  (ws + OFF_GRP);
  double* p1   = (double*)(ws + OFF_P1);
  double* p2   = (double*)(ws + OFF_P2);
  double* p3   = (double*)(ws + OFF_P3);
  float*  mr1  = (float*)(ws + OFF_MR1);
  float*  mr2  = (float*)(ws + OFF_MR2);
  float*  mr3  = (float*)(ws + OFF_MR3);
  float*  z3w  = (float*)(ws + OFF_Z3);
  float*  z2w  = (float*)(ws + OFF_Z2);

  const bool stz3 = (ws_size >= NEED_Z3);
  const bool stz2 = (ws_size >= NEED_Z2);   // implies stz3

  hipMemsetAsync(ws + OFF_P1, 0, 32768+32768+65536, stream);

  fps_kernel <<<BB, 512, 0, stream>>>(xyz, out, nxyz);
  ball_kernel<<<NGRP*64/256, 256, 0, stream>>>(xyz, nxyz, grp);

#define MLP_ARGS xyz, pts, nxyz, grp, w0, b0, mr1, g0, be0, w1, b1, mr2, g1, be1, w2, b2, mr3, g2, be2
  mlp_kernel<1,false,false><<<NPIX/64, 256, 0, stream>>>(MLP_ARGS, p1, out1, z2w, z3w);
  finalize_kernel<<<1,128,0,stream>>>(p1, mr1, 64);
  if (stz2) mlp_kernel<2,false,true ><<<NPIX/64, 256, 0, stream>>>(MLP_ARGS, p2, out1, z2w, z3w);
  else      mlp_kernel<2,false,false><<<NPIX/64, 256, 0, stream>>>(MLP_ARGS, p2, out1, z2w, z3w);
  finalize_kernel<<<1,128,0,stream>>>(p2, mr2, 64);
  if (stz2)      mlp_kernel<3,true ,true ><<<NPIX/64, 256, 0, stream>>>(MLP_ARGS, p3, out1, z2w, z3w);
  else if (stz3) mlp_kernel<3,true ,false><<<NPIX/64, 256, 0, stream>>>(MLP_ARGS, p3, out1, z2w, z3w);
  else           mlp_kernel<3,false,false><<<NPIX/64, 256, 0, stream>>>(MLP_ARGS, p3, out1, z2w, z3w);
  finalize_kernel<<<1,128,0,stream>>>(p3, mr3, 128);
  if (stz3) maxpool_kernel<<<NGRP/2, 256, 0, stream>>>(z3w, mr3, g2, be2, out1);
  else      mlp_kernel<4,false,false><<<NPIX/64, 256, 0, stream>>>(MLP_ARGS, p3, out1, z2w, z3w);
#undef MLP_ARGS
}